// Round 1
// baseline (368.470 us; speedup 1.0000x reference)
//
#include <hip/hip_runtime.h>
#include <math.h>

#define PI_F 3.14159265358979323846f

// ---------- complex helpers ----------
__device__ __forceinline__ float2 cadd(float2 a, float2 b){ return make_float2(a.x+b.x, a.y+b.y); }
__device__ __forceinline__ float2 csub(float2 a, float2 b){ return make_float2(a.x-b.x, a.y-b.y); }
__device__ __forceinline__ float2 cmul(float2 a, float2 b){ return make_float2(a.x*b.x - a.y*b.y, a.x*b.y + a.y*b.x); }
__device__ __forceinline__ float2 cscale(float2 a, float s){ return make_float2(a.x*s, a.y*s); }
__device__ __forceinline__ float clip01(float v){ return fminf(fmaxf(v, 0.0f), 1.0f); }

// Real-FFT unpack: given Z[k], Z[M-k] of the packed complex FFT (length M),
// produce U[k], U[M-k] of the length-2M real FFT. sn,cs = sincos(2*pi*k/(2M)).
__device__ __forceinline__ void unpack_pair(float2 Zk, float2 Zm, float sn, float cs,
                                            float2& Uk, float2& Um) {
  float2 A  = make_float2(0.5f*(Zk.x+Zm.x), 0.5f*(Zk.y-Zm.y)); // (Zk + conj(Zm))/2
  float2 B  = make_float2(Zk.x-Zm.x, Zk.y+Zm.y);               // Zk - conj(Zm)
  Uk = cadd(A, cmul(B, make_float2(-0.5f*sn, -0.5f*cs)));      // A + (-i/2)e^{-i th} B
  float2 Bm = make_float2(-B.x, B.y);                          // -conj(B)
  Um = cadd(make_float2(A.x, -A.y), cmul(Bm, make_float2(-0.5f*sn, 0.5f*cs)));
}

// Real-iFFT repack: given half-spectrum values V[k], V[M-k] (length-2M real irfft),
// produce W[k], W[M-k] to feed the length-M complex inverse FFT.
__device__ __forceinline__ void repack_pair(float2 Vk, float2 Vm, float sn, float cs,
                                            float2& Wk, float2& Wm) {
  float2 P = make_float2(Vk.x+Vm.x, Vk.y-Vm.y);   // Vk + conj(Vm)
  float2 Q = make_float2(Vk.x-Vm.x, Vk.y+Vm.y);   // Vk - conj(Vm)
  Wk = cscale(cadd(P, cmul(Q, make_float2(-sn, cs))), 0.5f);   // (P + i e^{+i th} Q)/2
  float2 Qm = make_float2(-Q.x, Q.y);             // -conj(Q)
  Wm = cscale(cadd(make_float2(P.x, -P.y), cmul(Qm, make_float2(-sn, -cs))), 0.5f);
}

// piecewise-linear interp of 16 coeffs to 16385 bins (torch linear, align_corners=False)
__device__ __forceinline__ float sshape(int k, const float* ncs) {
  float pos = ((float)k + 0.5f) * (16.0f/16385.0f) - 0.5f;
  pos = fminf(fmaxf(pos, 0.0f), 15.0f);
  float fi = floorf(pos);
  int i0 = (int)fi;
  int i1 = min(i0 + 1, 15);
  float w = pos - fi;
  return ncs[i0]*(1.0f-w) + ncs[i1]*w;
}

// ---------- kernel 1: zero the output accumulator ----------
__global__ void __launch_bounds__(1024, 1)
atoms_zero(float* __restrict__ out) {
  out[blockIdx.x * 1024 + threadIdx.x] = 0.0f;   // grid sized exactly: 1024*1024 = 1048576
}

// ---------- kernel 2: the fused per-(b,e) pipeline ----------
__global__ void __launch_bounds__(1024, 1)
atoms_main(const float* __restrict__ x, const float* __restrict__ noise,
           float* __restrict__ outacc) {
  const int blk = blockIdx.x;        // 0..511 = b*16 + e
  const int b   = blk >> 4;
  const int tid = threadIdx.x;

  const float* xr = x + (size_t)blk * 533;
  const float* nr = noise + (size_t)blk * 32768;

  __shared__ float2 C[16384];       // 131072 B : big FFT buffer / nband
  __shared__ float2 FR[8][256];     //  16384 B : 8 frame FFTs
  __shared__ float  magbuf[8][257]; //   8224 B : frame mags -> scanned mags
  __shared__ float  resmag[257];
  __shared__ float  resphase[257];
  __shared__ float  msarr[257];     // running scan state across frame groups
  __shared__ float  carry[256];     // OLA carry (prev frame second half)
  __shared__ float  ncs[16];        // noise_coeff

  // ---- per-(b,e) scalar params (every thread computes; reads are L1/L2 broadcast) ----
  const float xc0 = clip01(xr[0]);
  const float xc1 = clip01(xr[1]);
  const float amp = clip01(xr[2]);
  const float mean = xc0 * 2.0f - 1.0f;
  const float stdv = xc1 * 0.1f;
  float mu = fminf(fmaxf(mean * 32768.0f, -16384.0f), 49152.0f);
  float sigma = fminf(fmaxf((1e-8f + stdv) * 32768.0f, 0.0f), 32767.0f);
  const float K = -logf(sigma) - 0.91893853320467274f;   // -log(sigma) - 0.5 log(2 pi)
  const float invsig = 1.0f / sigma;
  float istar = fminf(fmaxf(roundf(mu), 0.0f), 32767.0f);
  float ds = (istar - mu) * invsig;
  float emax = __expf(-0.5f * ds * ds + K);
  const float gscale = amp / (emax + 1e-8f);

  // ---- param arrays ----
  for (int k = tid; k < 257; k += 1024) {
    resmag[k]   = 0.01f + 0.99f * clip01(xr[3 + k]);
    resphase[k] = clip01(xr[260 + k]) * (2.0f*PI_F) - PI_F + (float)k * (PI_F / 512.0f);
    msarr[k]    = 0.0f;
  }
  if (tid < 16)  ncs[tid]   = clip01(xr[517 + tid]);
  if (tid < 256) carry[tid] = 0.0f;

  // ---- load noise, u = 2*noise-1, packed z[j] = u[2j] + i u[2j+1] ----
  const float2* nr2 = (const float2*)nr;
  for (int j = tid; j < 16384; j += 1024) {
    float2 v = nr2[j];
    C[j] = make_float2(v.x * 2.0f - 1.0f, v.y * 2.0f - 1.0f);
  }
  __syncthreads();

  // ---- forward DIF complex FFT, 16384 pts, natural in -> bit-reversed out ----
  for (int s = 0; s < 14; ++s) {
    const int half = 8192 >> s;
    const float angc = -PI_F / (float)half;   // -2*pi/len
    for (int t = tid; t < 8192; t += 1024) {
      int j = t & (half - 1);
      int p = ((t >> (13 - s)) << (14 - s)) + j;
      float2 a = C[p], bb = C[p + half];
      float sn, cs; __sincosf(angc * (float)j, &sn, &cs);
      C[p] = cadd(a, bb);
      float2 d = csub(a, bb);
      C[p + half] = make_float2(d.x*cs - d.y*sn, d.x*sn + d.y*cs);
    }
    __syncthreads();
  }

  // ---- unpack rfft32768, multiply spec_shape, repack for irfft (in BR order) ----
  {
    const float invM = 1.0f / 16384.0f;   // folds ortho fwd+inv (1/N) and packing (1/M with /2s explicit)
    for (int k = tid; k <= 8192; k += 1024) {
      if (k == 0) {
        float2 Z0 = C[0];
        float U0 = Z0.x + Z0.y;            // bin 0 (real)
        float UM = Z0.x - Z0.y;            // bin 16384 (real)
        float V0 = U0 * sshape(0, ncs) * invM;
        float VM = UM * sshape(16384, ncs) * invM;
        C[0] = make_float2(0.5f*(V0+VM), 0.5f*(V0-VM));
      } else {
        int pk = (int)(__brev((unsigned)k) >> 18);
        int pm = (int)(__brev((unsigned)(16384 - k)) >> 18);
        float2 Zk = C[pk], Zm = C[pm];
        float sn, cs; __sincosf((float)k * (PI_F / 16384.0f), &sn, &cs);
        float2 Uk, Um; unpack_pair(Zk, Zm, sn, cs, Uk, Um);
        float2 Vk = cscale(Uk, sshape(k, ncs) * invM);
        float2 Vm = cscale(Um, sshape(16384 - k, ncs) * invM);
        float2 Wk, Wm; repack_pair(Vk, Vm, sn, cs, Wk, Wm);
        C[pk] = Wk; C[pm] = Wm;
      }
    }
  }
  __syncthreads();

  // ---- inverse DIT complex FFT, bit-reversed in -> natural out; C now holds nband pairs ----
  for (int s = 0; s < 14; ++s) {
    const int half = 1 << s;
    const float angc = PI_F / (float)half;    // +2*pi/len
    for (int t = tid; t < 8192; t += 1024) {
      int j = t & (half - 1);
      int p = ((t >> s) << (s + 1)) + j;
      float sn, cs; __sincosf(angc * (float)j, &sn, &cs);
      float2 a = C[p];
      float2 bb = cmul(C[p + half], make_float2(cs, sn));
      C[p] = cadd(a, bb);
      C[p + half] = csub(a, bb);
    }
    __syncthreads();
  }

  // ---- STFT frame loop: 16 groups of 8 frames ----
  const float C2 = 0.044194173824159216f;  // 1/sqrt(512)  (ortho fwd)
  const float F2 = 0.08838834764831845f;   // sqrt(512)/256 (ortho inv + packing)
  const float W512 = 2.0f * PI_F / 512.0f;

  for (int g = 0; g < 16; ++g) {
    // pack 8 frames: FR[i][j] = (atom(n0)*ham(2j), atom(n0+1)*ham(2j+1))
    for (int slot = tid; slot < 2048; slot += 1024) {
      int i = slot >> 8, j = slot & 255;
      int fg = g * 8 + i;
      int n0 = fg * 256 + 2 * j;
      float v0 = 0.0f, v1 = 0.0f;
      if (n0 < 32768) {
        float2 nb = C[n0 >> 1];
        float d0 = ((float)n0 - mu) * invsig;
        float d1 = ((float)(n0 + 1) - mu) * invsig;
        v0 = __expf(-0.5f * d0 * d0 + K) * gscale * nb.x;
        v1 = __expf(-0.5f * d1 * d1 + K) * gscale * nb.y;
      }
      float t0 = (float)(2 * j);
      float w0 = 0.54f - 0.46f * __cosf(t0 * W512);
      float w1 = 0.54f - 0.46f * __cosf((t0 + 1.0f) * W512);
      FR[i][j] = make_float2(v0 * w0, v1 * w1);
    }
    __syncthreads();

    // forward DIF, 8 x 256-pt (1024 butterflies/stage: all threads active)
    for (int s = 0; s < 8; ++s) {
      const int half = 128 >> s;
      const float angc = -PI_F / (float)half;
      int i = tid >> 7, tt = tid & 127;
      int j = tt & (half - 1);
      int p = ((tt >> (7 - s)) << (8 - s)) + j;
      float2 a = FR[i][p], bb = FR[i][p + half];
      float sn, cs; __sincosf(angc * (float)j, &sn, &cs);
      FR[i][p] = cadd(a, bb);
      float2 d = csub(a, bb);
      FR[i][p + half] = make_float2(d.x*cs - d.y*sn, d.x*sn + d.y*cs);
      __syncthreads();
    }

    // step A: magnitudes of all 257 bins x 8 frames
    for (int slot = tid; slot < 1032; slot += 1024) {
      int i = slot / 129;
      int k = slot - i * 129;
      if (k == 0) {
        float2 Z0 = FR[i][0];
        float U0 = Z0.x + Z0.y, UM = Z0.x - Z0.y;
        magbuf[i][0]   = fabsf(U0) * C2 + 1e-8f;
        magbuf[i][256] = fabsf(UM) * C2 + 1e-8f;
      } else {
        int pk = (int)(__brev((unsigned)k) >> 24);
        int pm = (int)(__brev((unsigned)(256 - k)) >> 24);
        float sn, cs; __sincosf((float)k * (PI_F / 256.0f), &sn, &cs);
        float2 Uk, Um; unpack_pair(FR[i][pk], FR[i][pm], sn, cs, Uk, Um);
        magbuf[i][k]       = sqrtf(Uk.x*Uk.x + Uk.y*Uk.y) * C2 + 1e-8f;
        magbuf[i][256 - k] = sqrtf(Um.x*Um.x + Um.y*Um.y) * C2 + 1e-8f;
      }
    }
    __syncthreads();

    // step B: sequential magnitude scan across the 8 frames (per bin)
    if (tid < 257) {
      float r = msarr[tid];
      float rm = resmag[tid];
      #pragma unroll
      for (int i = 0; i < 8; ++i) {
        r = magbuf[i][tid] + rm * r;
        magbuf[i][tid] = r;         // overwrite with scanned value
      }
      msarr[tid] = r;
    }
    __syncthreads();

    // step C: rebuild spectrum V = ms * exp(i*(phase + fmask*res_phase)), repack, in place
    for (int slot = tid; slot < 1032; slot += 1024) {
      int i = slot / 129;
      int k = slot - i * 129;
      int fg = g * 8 + i;
      float fm = (fg > 0) ? 1.0f : 0.0f;
      if (k == 0) {
        // DC & Nyquist: spec imag is exactly 0 -> phase = fmask*res_phase; irfft drops imag
        float ph0 = fm * resphase[0];
        float phM = fm * resphase[256];
        float V0 = magbuf[i][0]   * F2 * __cosf(ph0);
        float VM = magbuf[i][256] * F2 * __cosf(phM);
        FR[i][0] = make_float2(0.5f*(V0+VM), 0.5f*(V0-VM));
      } else {
        int pk = (int)(__brev((unsigned)k) >> 24);
        int pm = (int)(__brev((unsigned)(256 - k)) >> 24);
        float sn, cs; __sincosf((float)k * (PI_F / 256.0f), &sn, &cs);
        float2 Uk, Um; unpack_pair(FR[i][pk], FR[i][pm], sn, cs, Uk, Um);

        float magk = sqrtf(Uk.x*Uk.x + Uk.y*Uk.y) * C2 + 1e-8f;
        float phk  = (Uk.y * C2 / magk) * PI_F + fm * resphase[k];
        float msk  = magbuf[i][k] * F2;
        float snk, csk; __sincosf(phk, &snk, &csk);
        float2 Vk = make_float2(msk * csk, msk * snk);

        float magm = sqrtf(Um.x*Um.x + Um.y*Um.y) * C2 + 1e-8f;
        float phm  = (Um.y * C2 / magm) * PI_F + fm * resphase[256 - k];
        float msm  = magbuf[i][256 - k] * F2;
        float snm, csm; __sincosf(phm, &snm, &csm);
        float2 Vm = make_float2(msm * csm, msm * snm);

        float2 Wk, Wm; repack_pair(Vk, Vm, sn, cs, Wk, Wm);
        FR[i][pk] = Wk; FR[i][pm] = Wm;
      }
    }
    __syncthreads();

    // inverse DIT, 8 x 256-pt -> res samples (natural order)
    for (int s = 0; s < 8; ++s) {
      const int half = 1 << s;
      const float angc = PI_F / (float)half;
      int i = tid >> 7, tt = tid & 127;
      int j = tt & (half - 1);
      int p = ((tt >> s) << (s + 1)) + j;
      float sn, cs; __sincosf(angc * (float)j, &sn, &cs);
      float2 a = FR[i][p];
      float2 bb = cmul(FR[i][p + half], make_float2(cs, sn));
      FR[i][p] = cadd(a, bb);
      FR[i][p + half] = csub(a, bb);
      __syncthreads();
    }

    // overlap-add emit: chunk(fg)[t] = res_fg[t] + res_{fg-1}[256+t]
    for (int slot = tid; slot < 2048; slot += 1024) {
      int i = slot >> 8, t = slot & 255;
      float second;
      if (i == 0) {
        second = carry[t];
      } else {
        float2 pr = FR[i - 1][128 + (t >> 1)];
        second = (t & 1) ? pr.y : pr.x;
      }
      float2 cur = FR[i][t >> 1];
      float first = (t & 1) ? cur.y : cur.x;
      int pos = (g * 8 + i) * 256 + t;
      atomicAdd(&outacc[(size_t)b * 32768 + pos], first + second);
    }
    __syncthreads();

    // update carry = last frame's second half
    if (tid < 256) {
      float2 pr = FR[7][128 + (tid >> 1)];
      carry[tid] = (tid & 1) ? pr.y : pr.x;
    }
    __syncthreads();
  }
}

// ---------- kernel 3: per-batch max-abs normalize (in place) ----------
__global__ void __launch_bounds__(1024, 1)
atoms_norm(float* __restrict__ out) {
  const int b = blockIdx.x;
  const int tid = threadIdx.x;
  float* p = out + (size_t)b * 32768;
  __shared__ float red[1024];
  float m = 0.0f;
  for (int i = tid; i < 32768; i += 1024) m = fmaxf(m, fabsf(p[i]));
  red[tid] = m;
  __syncthreads();
  for (int s = 512; s > 0; s >>= 1) {
    if (tid < s) red[tid] = fmaxf(red[tid], red[tid + s]);
    __syncthreads();
  }
  const float inv = 1.0f / (red[0] + 1e-8f);
  for (int i = tid; i < 32768; i += 1024) p[i] = p[i] * inv;
}

extern "C" void kernel_launch(void* const* d_in, const int* in_sizes, int n_in,
                              void* d_out, int out_size, void* d_ws, size_t ws_size,
                              hipStream_t stream) {
  (void)in_sizes; (void)n_in; (void)d_ws; (void)ws_size; (void)out_size;
  const float* x     = (const float*)d_in[0];
  const float* noise = (const float*)d_in[1];
  float* out = (float*)d_out;

  atoms_zero<<<1024, 1024, 0, stream>>>(out);          // 32*1*32768 = 1048576 floats
  atoms_main<<<512, 1024, 0, stream>>>(x, noise, out); // one block per (b,e)
  atoms_norm<<<32, 1024, 0, stream>>>(out);            // per-batch max_norm
}